// Round 1
// baseline (622.609 us; speedup 1.0000x reference)
//
#include <hip/hip_runtime.h>

#define NHID 128
#define K1   384
#define BM   128
#define LDA  72    // 64 + 8 pad (elements)
#define LDE  136   // 128 + 8 pad (elements)

typedef __attribute__((ext_vector_type(8))) short short8;
typedef __attribute__((ext_vector_type(4))) float f32x4;

__device__ inline unsigned short f2bf(float f) {
    unsigned int u = __float_as_uint(f);
    u += 0x7fffu + ((u >> 16) & 1u);   // round-to-nearest-even
    return (unsigned short)(u >> 16);
}
__device__ inline float bf2f(unsigned short h) {
    return __uint_as_float(((unsigned int)h) << 16);
}

// Convert weights fp32 -> bf16, transposed to [N][K] (B-fragment wants 8
// contiguous k at row n). Also autodetect edge_index int64-vs-int32:
// if int64 (values < 1e5 >= 0), every odd 32-bit word of the first 64
// elements is 0.
__global__ void prep_kernel(const float* __restrict__ Wm, const float* __restrict__ We,
                            const int* __restrict__ eidx_raw,
                            unsigned short* __restrict__ wt_msg,
                            unsigned short* __restrict__ wt_edge,
                            int* __restrict__ flag) {
    int i = blockIdx.x * 256 + threadIdx.x;
    if (i < NHID * K1) {
        int n = i / K1, k = i - n * K1;
        wt_msg[i] = f2bf(Wm[k * NHID + n]);
    }
    if (i < NHID * NHID) {
        int n = i >> 7, k = i & 127;
        wt_edge[i] = f2bf(We[k * NHID + n]);
    }
    if (blockIdx.x == 0) {
        __shared__ int nz;
        if (threadIdx.x == 0) nz = 0;
        __syncthreads();
        if (threadIdx.x < 64) {
            if (eidx_raw[threadIdx.x * 2 + 1] != 0) atomicAdd(&nz, 1);
        }
        __syncthreads();
        if (threadIdx.x == 0) flag[0] = (nz == 0) ? 1 : 0;   // 1 => int64
    }
}

__global__ __launch_bounds__(256) void edge_conv_kernel(
    const float* __restrict__ x, const float* __restrict__ eattr,
    const int* __restrict__ ip,               // edge_index raw words
    const float* __restrict__ bmsg, const float* __restrict__ bedge,
    const unsigned short* __restrict__ wmsg,  // [128][384] bf16 (W_msg^T)
    const unsigned short* __restrict__ wedge, // [128][128] bf16 (W_edge^T)
    const int* __restrict__ flag,
    float* __restrict__ out, int E)
{
    __shared__ __align__(16) unsigned short sA[BM * LDA];   // 18432 B
    __shared__ __align__(16) unsigned short sEA[BM * LDE];  // 34816 B
    __shared__ int sIdx[2 * BM];                            // 1024 B

    const int tid  = threadIdx.x;
    const int lane = tid & 63;
    const int wave = tid >> 6;
    const int wm   = wave >> 1;   // row quadrant (0..1)
    const int wn   = wave & 1;    // col quadrant (0..1)
    const int l15  = lane & 15;
    const int l4   = lane >> 4;   // 0..3
    const int e0   = blockIdx.x * BM;
    const int is64 = flag[0];

    // ---- load edge indices (low 32 bits if int64) ----
    {
        int t = tid;
        if (t < BM) {
            int e = e0 + t; if (e >= E) e = E - 1;
            sIdx[t] = is64 ? ip[2 * (long long)e] : ip[e];
        } else {
            int e = e0 + (t - BM); if (e >= E) e = E - 1;
            long long off = (long long)E + e;
            sIdx[t] = is64 ? ip[2 * off] : ip[off];
        }
    }
    __syncthreads();

    const int erow = tid >> 3;   // 0..31 : row within 32-row staging pass
    const int kg   = tid & 7;    // 0..7  : 8-float column group

    int ridx[4], cidx[4];
    #pragma unroll
    for (int p = 0; p < 4; ++p) {
        ridx[p] = sIdx[p * 32 + erow];
        cidx[p] = sIdx[BM + p * 32 + erow];
    }

    f32x4 acc[4][4];
    #pragma unroll
    for (int mt = 0; mt < 4; ++mt)
        #pragma unroll
        for (int nt = 0; nt < 4; ++nt)
            acc[mt][nt] = (f32x4){0.f, 0.f, 0.f, 0.f};

    // ================= GEMM1: K = 384 in 6 chunks of 64 =================
    for (int c = 0; c < 6; ++c) {
        const int s  = c >> 1;          // 0: x[row], 1: x[col], 2: edge_attr
        const int ko = (c & 1) * 64;
        __syncthreads();
        // ---- stage 128x64 fp32 -> bf16 ----
        #pragma unroll
        for (int p = 0; p < 4; ++p) {
            int el = p * 32 + erow;
            int e  = e0 + el; if (e >= E) e = E - 1;
            const float* src;
            if (s == 0)      src = x + (size_t)ridx[p] * NHID;
            else if (s == 1) src = x + (size_t)cidx[p] * NHID;
            else             src = eattr + (size_t)e * NHID;
            const float4* sp = (const float4*)(src + ko + kg * 8);
            float4 f0 = sp[0], f1 = sp[1];
            short8 hv;
            hv[0] = (short)f2bf(f0.x); hv[1] = (short)f2bf(f0.y);
            hv[2] = (short)f2bf(f0.z); hv[3] = (short)f2bf(f0.w);
            hv[4] = (short)f2bf(f1.x); hv[5] = (short)f2bf(f1.y);
            hv[6] = (short)f2bf(f1.z); hv[7] = (short)f2bf(f1.w);
            unsigned short* dst = (s < 2) ? &sA[el * LDA + kg * 8]
                                          : &sEA[el * LDE + ko + kg * 8];
            *(short8*)dst = hv;
        }
        __syncthreads();
        // ---- compute ----
        const unsigned short* abase = (s < 2) ? &sA[0] : &sEA[ko];
        const int lda = (s < 2) ? LDA : LDE;
        #pragma unroll
        for (int kk = 0; kk < 2; ++kk) {
            short8 af[4], bfr[4];
            #pragma unroll
            for (int mt = 0; mt < 4; ++mt) {
                int r = wm * 64 + mt * 16 + l15;
                af[mt] = *(const short8*)(abase + r * lda + kk * 32 + l4 * 8);
            }
            #pragma unroll
            for (int nt = 0; nt < 4; ++nt) {
                int n = wn * 64 + nt * 16 + l15;
                bfr[nt] = *(const short8*)(wmsg + n * K1 + c * 64 + kk * 32 + l4 * 8);
            }
            #pragma unroll
            for (int mt = 0; mt < 4; ++mt)
                #pragma unroll
                for (int nt = 0; nt < 4; ++nt)
                    acc[mt][nt] = __builtin_amdgcn_mfma_f32_16x16x32_bf16(
                        af[mt], bfr[nt], acc[mt][nt], 0, 0, 0);
        }
    }

    __syncthreads();
    // ===== epilogue 1: ea = edge_attr + relu(msg + b_msg), bf16 into sEA =====
    {
        float bm[4];
        #pragma unroll
        for (int nt = 0; nt < 4; ++nt) bm[nt] = bmsg[wn * 64 + nt * 16 + l15];
        #pragma unroll
        for (int mt = 0; mt < 4; ++mt) {
            int rbase = wm * 64 + mt * 16 + l4 * 4;
            #pragma unroll
            for (int nt = 0; nt < 4; ++nt) {
                int ccol = wn * 64 + nt * 16 + l15;
                #pragma unroll
                for (int r = 0; r < 4; ++r) {
                    float m = acc[mt][nt][r] + bm[nt];
                    m = fmaxf(m, 0.f);
                    int idx = (rbase + r) * LDE + ccol;
                    float ea = bf2f(sEA[idx]) + m;
                    sEA[idx] = f2bf(ea);
                    acc[mt][nt][r] = 0.f;   // reset for GEMM2
                }
            }
        }
    }
    __syncthreads();

    // ================= GEMM2: K = 128, A = sEA =================
    #pragma unroll
    for (int kk = 0; kk < 4; ++kk) {
        short8 af[4], bfr[4];
        #pragma unroll
        for (int mt = 0; mt < 4; ++mt) {
            int r = wm * 64 + mt * 16 + l15;
            af[mt] = *(const short8*)(&sEA[r * LDE + kk * 32 + l4 * 8]);
        }
        #pragma unroll
        for (int nt = 0; nt < 4; ++nt) {
            int n = wn * 64 + nt * 16 + l15;
            bfr[nt] = *(const short8*)(wedge + n * NHID + kk * 32 + l4 * 8);
        }
        #pragma unroll
        for (int mt = 0; mt < 4; ++mt)
            #pragma unroll
            for (int nt = 0; nt < 4; ++nt)
                acc[mt][nt] = __builtin_amdgcn_mfma_f32_16x16x32_bf16(
                    af[mt], bfr[nt], acc[mt][nt], 0, 0, 0);
    }

    // ===== epilogue 2: out = relu(acc + b_edge), fp32 stores =====
    {
        float bb[4];
        #pragma unroll
        for (int nt = 0; nt < 4; ++nt) bb[nt] = bedge[wn * 64 + nt * 16 + l15];
        #pragma unroll
        for (int mt = 0; mt < 4; ++mt) {
            int rbase = wm * 64 + mt * 16 + l4 * 4;
            #pragma unroll
            for (int r = 0; r < 4; ++r) {
                int e = e0 + rbase + r;
                if (e < E) {
                    float* op = out + (size_t)e * NHID + wn * 64 + l15;
                    #pragma unroll
                    for (int nt = 0; nt < 4; ++nt)
                        op[nt * 16] = fmaxf(acc[mt][nt][r] + bb[nt], 0.f);
                }
            }
        }
    }
}

extern "C" void kernel_launch(void* const* d_in, const int* in_sizes, int n_in,
                              void* d_out, int out_size, void* d_ws, size_t ws_size,
                              hipStream_t stream) {
    const float* x     = (const float*)d_in[0];
    const float* eattr = (const float*)d_in[1];
    const int*   eidx  = (const int*)d_in[2];   // raw words; int64-vs-int32 autodetected
    const float* Wm    = (const float*)d_in[3];
    const float* bm    = (const float*)d_in[4];
    const float* We    = (const float*)d_in[5];
    const float* be    = (const float*)d_in[6];
    float* out = (float*)d_out;

    const int E = in_sizes[2] / 2;   // edge_index has 2*E elements

    unsigned short* wmsg  = (unsigned short*)d_ws;            // 128*384 bf16
    unsigned short* wedge = wmsg + NHID * K1;                 // 128*128 bf16
    int* flag = (int*)(wedge + NHID * NHID);

    prep_kernel<<<(NHID * K1 + 255) / 256, 256, 0, stream>>>(Wm, We, eidx, wmsg, wedge, flag);

    int nblocks = (E + BM - 1) / BM;
    edge_conv_kernel<<<nblocks, 256, 0, stream>>>(x, eattr, eidx, bm, be,
                                                  wmsg, wedge, flag, out, E);
}

// Round 2
// 555.041 us; speedup vs baseline: 1.1217x; 1.1217x over previous
//
#include <hip/hip_runtime.h>

#define NHID 128
#define BM   128
#define LDE  136   // 128 + 8 pad: row stride 272 B = 17*16 B (odd multiple of 16)

typedef __attribute__((ext_vector_type(8))) short short8;
typedef __attribute__((ext_vector_type(4))) float f32x4;

__device__ inline unsigned short f2bf(float f) {
    unsigned int u = __float_as_uint(f);
    u += 0x7fffu + ((u >> 16) & 1u);   // round-to-nearest-even
    return (unsigned short)(u >> 16);
}
__device__ inline float bf2f(unsigned short h) {
    return __uint_as_float(((unsigned int)h) << 16);
}

// ---- prep: convert/transpose weights to bf16, detect int64 edge_index ----
// wtp [256][128]: rows 0..127 = W_msg[k][n] (x[row] slice), rows 128..255 = W_msg[128+k][n]
// wt3 [128][128]: W_msg[256+k][n]    wte [128][128]: W_edge[k][n]
__global__ void prep_kernel(const float* __restrict__ Wm, const float* __restrict__ We,
                            const int* __restrict__ eidx_raw,
                            unsigned short* __restrict__ wtp,
                            unsigned short* __restrict__ wt3,
                            unsigned short* __restrict__ wte,
                            int* __restrict__ flag) {
    int i = blockIdx.x * 256 + threadIdx.x;
    if (i < 256 * NHID) {
        int nn = i >> 7, k = i & 127;
        float v = (nn < 128) ? Wm[k * NHID + nn] : Wm[(128 + k) * NHID + (nn - 128)];
        wtp[i] = f2bf(v);
    }
    if (i < NHID * NHID) {
        int n = i >> 7, k = i & 127;
        wt3[i] = f2bf(Wm[(256 + k) * NHID + n]);
        wte[i] = f2bf(We[k * NHID + n]);
    }
    if (blockIdx.x == 0) {
        __shared__ int nz;
        if (threadIdx.x == 0) nz = 0;
        __syncthreads();
        if (threadIdx.x < 64) {
            if (eidx_raw[threadIdx.x * 2 + 1] != 0) atomicAdd(&nz, 1);
        }
        __syncthreads();
        if (threadIdx.x == 0) flag[0] = (nz == 0) ? 1 : 0;   // 1 => int64
    }
}

// ---- node projection: Xp[n][0:128]=x[n]@W1, Xp[n][128:256]=x[n]@W2 (bf16) ----
__global__ __launch_bounds__(256, 4) void proj_kernel(
    const float* __restrict__ x, const unsigned short* __restrict__ wtp,
    unsigned short* __restrict__ xp, int N)
{
    __shared__ __align__(16) unsigned short sX[BM * LDE];

    const int tid  = threadIdx.x;
    const int lane = tid & 63;
    const int wave = tid >> 6;
    const int wm   = wave >> 1, wn = wave & 1;
    const int l15  = lane & 15, l4 = lane >> 4;
    const int n0   = blockIdx.x * BM;
    const int half = blockIdx.y;          // 0: W1, 1: W2

    // stage x rows fp32 -> bf16
    const int erow = tid >> 4, kg = tid & 15;
    #pragma unroll
    for (int p = 0; p < 8; ++p) {
        int el = p * 16 + erow;
        int n  = n0 + el; if (n >= N) n = N - 1;
        const float4* sp = (const float4*)(x + (size_t)n * NHID + kg * 8);
        float4 f0 = sp[0], f1 = sp[1];
        short8 hv;
        hv[0] = (short)f2bf(f0.x); hv[1] = (short)f2bf(f0.y);
        hv[2] = (short)f2bf(f0.z); hv[3] = (short)f2bf(f0.w);
        hv[4] = (short)f2bf(f1.x); hv[5] = (short)f2bf(f1.y);
        hv[6] = (short)f2bf(f1.z); hv[7] = (short)f2bf(f1.w);
        *(short8*)&sX[el * LDE + kg * 8] = hv;
    }
    __syncthreads();

    f32x4 acc[4][4];
    #pragma unroll
    for (int mt = 0; mt < 4; ++mt)
        #pragma unroll
        for (int nt = 0; nt < 4; ++nt) acc[mt][nt] = (f32x4){0.f,0.f,0.f,0.f};

    const unsigned short* wb = wtp + half * NHID * NHID;
    #pragma unroll
    for (int kk = 0; kk < 4; ++kk) {
        short8 af[4], bfr[4];
        #pragma unroll
        for (int mt = 0; mt < 4; ++mt) {
            int r = wm * 64 + mt * 16 + l15;
            af[mt] = *(const short8*)(&sX[r * LDE + kk * 32 + l4 * 8]);
        }
        #pragma unroll
        for (int nt = 0; nt < 4; ++nt) {
            int n = wn * 64 + nt * 16 + l15;
            bfr[nt] = *(const short8*)(wb + n * NHID + kk * 32 + l4 * 8);
        }
        #pragma unroll
        for (int mt = 0; mt < 4; ++mt)
            #pragma unroll
            for (int nt = 0; nt < 4; ++nt)
                acc[mt][nt] = __builtin_amdgcn_mfma_f32_16x16x32_bf16(
                    af[mt], bfr[nt], acc[mt][nt], 0, 0, 0);
    }

    // write bf16
    #pragma unroll
    for (int mt = 0; mt < 4; ++mt) {
        int rbase = wm * 64 + mt * 16 + l4 * 4;
        #pragma unroll
        for (int r = 0; r < 4; ++r) {
            int n = n0 + rbase + r;
            if (n < N) {
                unsigned short* op = xp + (size_t)n * 256 + half * NHID + wn * 64 + l15;
                #pragma unroll
                for (int nt = 0; nt < 4; ++nt)
                    op[nt * 16] = f2bf(acc[mt][nt][r]);
            }
        }
    }
}

// ---- main: per 128-edge tile ----
__global__ __launch_bounds__(256, 4) void edge_conv_kernel(
    const float* __restrict__ eattr,
    const int* __restrict__ ip,
    const float* __restrict__ bmsg, const float* __restrict__ bedge,
    const unsigned short* __restrict__ wt3,
    const unsigned short* __restrict__ wte,
    const unsigned short* __restrict__ xp,
    const int* __restrict__ flag,
    float* __restrict__ out, int E)
{
    __shared__ __align__(16) unsigned short sEA[BM * LDE];  // 34816 B
    __shared__ int sIdx[2 * BM];                            // 1024 B

    const int tid  = threadIdx.x;
    const int lane = tid & 63;
    const int wave = tid >> 6;
    const int wm   = wave >> 1, wn = wave & 1;
    const int l15  = lane & 15, l4 = lane >> 4;
    const int e0   = blockIdx.x * BM;
    const int is64 = flag[0];

    // edge indices (low words if int64)
    {
        int t = tid;
        if (t < BM) {
            int e = e0 + t; if (e >= E) e = E - 1;
            sIdx[t] = is64 ? ip[2 * (long long)e] : ip[e];
        } else {
            int e = e0 + (t - BM); if (e >= E) e = E - 1;
            long long off = (long long)E + e;
            sIdx[t] = is64 ? ip[2 * off] : ip[off];
        }
    }

    // stage edge_attr fp32 -> bf16 (contiguous 64 KB block read)
    const int erow = tid >> 4, kg = tid & 15;
    #pragma unroll
    for (int p = 0; p < 8; ++p) {
        int el = p * 16 + erow;
        int e  = e0 + el; if (e >= E) e = E - 1;
        const float4* sp = (const float4*)(eattr + (size_t)e * NHID + kg * 8);
        float4 f0 = sp[0], f1 = sp[1];
        short8 hv;
        hv[0] = (short)f2bf(f0.x); hv[1] = (short)f2bf(f0.y);
        hv[2] = (short)f2bf(f0.z); hv[3] = (short)f2bf(f0.w);
        hv[4] = (short)f2bf(f1.x); hv[5] = (short)f2bf(f1.y);
        hv[6] = (short)f2bf(f1.z); hv[7] = (short)f2bf(f1.w);
        *(short8*)&sEA[el * LDE + kg * 8] = hv;
    }
    __syncthreads();

    f32x4 acc[4][4];
    #pragma unroll
    for (int mt = 0; mt < 4; ++mt)
        #pragma unroll
        for (int nt = 0; nt < 4; ++nt) acc[mt][nt] = (f32x4){0.f,0.f,0.f,0.f};

    // GEMM1': edge_attr @ W3   (K = 128)
    #pragma unroll
    for (int kk = 0; kk < 4; ++kk) {
        short8 af[4], bfr[4];
        #pragma unroll
        for (int mt = 0; mt < 4; ++mt) {
            int r = wm * 64 + mt * 16 + l15;
            af[mt] = *(const short8*)(&sEA[r * LDE + kk * 32 + l4 * 8]);
        }
        #pragma unroll
        for (int nt = 0; nt < 4; ++nt) {
            int n = wn * 64 + nt * 16 + l15;
            bfr[nt] = *(const short8*)(wt3 + n * NHID + kk * 32 + l4 * 8);
        }
        #pragma unroll
        for (int mt = 0; mt < 4; ++mt)
            #pragma unroll
            for (int nt = 0; nt < 4; ++nt)
                acc[mt][nt] = __builtin_amdgcn_mfma_f32_16x16x32_bf16(
                    af[mt], bfr[nt], acc[mt][nt], 0, 0, 0);
    }
    __syncthreads();   // all waves done reading sEA before epilogue rewrites it

    // epilogue 1: ea = edge_attr + relu(acc + b_msg + Xp1[row] + Xp2[col])
    {
        float bm_[4];
        #pragma unroll
        for (int nt = 0; nt < 4; ++nt) bm_[nt] = bmsg[wn * 64 + nt * 16 + l15];
        #pragma unroll
        for (int mt = 0; mt < 4; ++mt) {
            int rbase = wm * 64 + mt * 16 + l4 * 4;
            #pragma unroll
            for (int r = 0; r < 4; ++r) {
                int row = rbase + r;
                int nr  = sIdx[row];
                int ncl = sIdx[BM + row];
                const unsigned short* g1 = xp + (size_t)nr  * 256 + wn * 64 + l15;
                const unsigned short* g2 = xp + (size_t)ncl * 256 + 128 + wn * 64 + l15;
                #pragma unroll
                for (int nt = 0; nt < 4; ++nt) {
                    float m = acc[mt][nt][r] + bm_[nt]
                            + bf2f(g1[nt * 16]) + bf2f(g2[nt * 16]);
                    m = fmaxf(m, 0.f);
                    int idx = row * LDE + wn * 64 + nt * 16 + l15;
                    sEA[idx] = f2bf(bf2f(sEA[idx]) + m);
                    acc[mt][nt][r] = 0.f;
                }
            }
        }
    }
    __syncthreads();

    // GEMM2: ea @ W_edge   (K = 128)
    #pragma unroll
    for (int kk = 0; kk < 4; ++kk) {
        short8 af[4], bfr[4];
        #pragma unroll
        for (int mt = 0; mt < 4; ++mt) {
            int r = wm * 64 + mt * 16 + l15;
            af[mt] = *(const short8*)(&sEA[r * LDE + kk * 32 + l4 * 8]);
        }
        #pragma unroll
        for (int nt = 0; nt < 4; ++nt) {
            int n = wn * 64 + nt * 16 + l15;
            bfr[nt] = *(const short8*)(wte + n * NHID + kk * 32 + l4 * 8);
        }
        #pragma unroll
        for (int mt = 0; mt < 4; ++mt)
            #pragma unroll
            for (int nt = 0; nt < 4; ++nt)
                acc[mt][nt] = __builtin_amdgcn_mfma_f32_16x16x32_bf16(
                    af[mt], bfr[nt], acc[mt][nt], 0, 0, 0);
    }

    // epilogue 2: out = relu(acc + b_edge)
    {
        float bb[4];
        #pragma unroll
        for (int nt = 0; nt < 4; ++nt) bb[nt] = bedge[wn * 64 + nt * 16 + l15];
        #pragma unroll
        for (int mt = 0; mt < 4; ++mt) {
            int rbase = wm * 64 + mt * 16 + l4 * 4;
            #pragma unroll
            for (int r = 0; r < 4; ++r) {
                int e = e0 + rbase + r;
                if (e < E) {
                    float* op = out + (size_t)e * NHID + wn * 64 + l15;
                    #pragma unroll
                    for (int nt = 0; nt < 4; ++nt)
                        op[nt * 16] = fmaxf(acc[mt][nt][r] + bb[nt], 0.f);
                }
            }
        }
    }
}

extern "C" void kernel_launch(void* const* d_in, const int* in_sizes, int n_in,
                              void* d_out, int out_size, void* d_ws, size_t ws_size,
                              hipStream_t stream) {
    const float* x     = (const float*)d_in[0];
    const float* eattr = (const float*)d_in[1];
    const int*   eidx  = (const int*)d_in[2];
    const float* Wm    = (const float*)d_in[3];
    const float* bm    = (const float*)d_in[4];
    const float* We    = (const float*)d_in[5];
    const float* be    = (const float*)d_in[6];
    float* out = (float*)d_out;

    const int N = in_sizes[0] / NHID;
    const int E = in_sizes[2] / 2;

    unsigned short* wtp = (unsigned short*)d_ws;        // 256*128
    unsigned short* wt3 = wtp + 256 * NHID;             // 128*128
    unsigned short* wte = wt3 + NHID * NHID;            // 128*128
    int* flag = (int*)(wte + NHID * NHID);
    unsigned short* xp  = (unsigned short*)(flag + 4);  // N*256 bf16 (~51 MB)

    prep_kernel<<<(256 * NHID + 255) / 256, 256, 0, stream>>>(Wm, We, eidx, wtp, wt3, wte, flag);

    dim3 pgrid((N + BM - 1) / BM, 2);
    proj_kernel<<<pgrid, 256, 0, stream>>>(x, wtp, xp, N);

    int nblocks = (E + BM - 1) / BM;
    edge_conv_kernel<<<nblocks, 256, 0, stream>>>(eattr, eidx, bm, be,
                                                  wt3, wte, xp, flag, out, E);
}